// Round 1
// baseline (432.045 us; speedup 1.0000x reference)
//
#include <hip/hip_runtime.h>
#include <math.h>

#define NH   16        // B*H = 2*8
#define SEQ  1024
#define DIM  64
#define MUV  (1.0f/1024.0f)   // mu = nu = 1/S

__device__ __forceinline__ float frcp(float x) { return __builtin_amdgcn_rcpf(x); }

// Kernel 1: Kmat[h][i][j] = exp(-exp(Q_i . K_j) / 8)
// 128x128 tile per block, 256 threads, 8x8 register micro-tile (rows ty+16i, cols tx+16j).
__global__ __launch_bounds__(256) void qk_kernel(const float* __restrict__ Q,
                                                 const float* __restrict__ Kin,
                                                 float* __restrict__ Kmat) {
  __shared__ __align__(16) float Qt[128][DIM + 4];
  __shared__ __align__(16) float Kt[128][DIM + 4];
  const int h  = blockIdx.z;
  const int r0 = blockIdx.y * 128;
  const int c0 = blockIdx.x * 128;
  const int t  = threadIdx.x;
  const int ty = t >> 4;    // 0..15
  const int tx = t & 15;    // 0..15
  const float* Qh = Q   + (size_t)h * SEQ * DIM;
  const float* Kh = Kin + (size_t)h * SEQ * DIM;

#pragma unroll
  for (int ro = 0; ro < 8; ro++) {
    const int r = ro * 16 + ty;
    *(float4*)&Qt[r][tx * 4] = *(const float4*)(Qh + (size_t)(r0 + r) * DIM + tx * 4);
    *(float4*)&Kt[r][tx * 4] = *(const float4*)(Kh + (size_t)(c0 + r) * DIM + tx * 4);
  }
  __syncthreads();

  float acc[8][8] = {};
#pragma unroll 2
  for (int d0 = 0; d0 < DIM; d0 += 4) {
    float4 qa[8], kb[8];
#pragma unroll
    for (int i = 0; i < 8; i++) qa[i] = *(const float4*)&Qt[ty + 16 * i][d0];
#pragma unroll
    for (int j = 0; j < 8; j++) kb[j] = *(const float4*)&Kt[tx + 16 * j][d0];
#pragma unroll
    for (int i = 0; i < 8; i++)
#pragma unroll
      for (int j = 0; j < 8; j++)
        acc[i][j] += qa[i].x * kb[j].x + qa[i].y * kb[j].y +
                     qa[i].z * kb[j].z + qa[i].w * kb[j].w;
  }

#pragma unroll
  for (int i = 0; i < 8; i++) {
    float* dst = Kmat + ((size_t)h * SEQ + r0 + ty + 16 * i) * SEQ + c0 + tx;
#pragma unroll
    for (int j = 0; j < 8; j++)
      dst[16 * j] = __expf(-__expf(acc[i][j]) * 0.125f);
  }
}

// Row pass: r_i = sum_j Kmat[i][j] * b_j,  b_j = (first ? 1 : nu / c_j).
// One wave per row; 4 rows per 256-thread block.
__global__ __launch_bounds__(256) void row_pass(const float* __restrict__ Kmat,
                                                const float* __restrict__ cvec,
                                                float* __restrict__ rvec,
                                                int first) {
  const int lane = threadIdx.x & 63;
  const int wid  = threadIdx.x >> 6;
  const int row  = blockIdx.x * 4 + wid;    // 0..NH*SEQ-1
  const int h    = row >> 10;
  const float* Krow = Kmat + (size_t)row * SEQ;
  const float* ch   = cvec + h * SEQ;
  float sum = 0.f;
#pragma unroll
  for (int k = 0; k < 4; k++) {
    const int c = k * 256 + lane * 4;
    const float4 kv = *(const float4*)(Krow + c);
    if (first) {
      sum += (kv.x + kv.y) + (kv.z + kv.w);
    } else {
      const float4 cv = *(const float4*)(ch + c);
      sum += kv.x * frcp(cv.x) + kv.y * frcp(cv.y) +
             kv.z * frcp(cv.z) + kv.w * frcp(cv.w);
    }
  }
  if (!first) sum *= MUV;   // fold nu out of the per-element divides
#pragma unroll
  for (int off = 32; off; off >>= 1) sum += __shfl_xor(sum, off);
  if (lane == 0) rvec[row] = sum;
}

// Col pass: c_j += sum_{i in 128-row chunk} Kmat[i][j] * (mu / r_i).
// grid = 16 heads * 4 col-chunks(256) * 8 row-chunks(128) = 512 blocks.
__global__ __launch_bounds__(256) void col_pass(const float* __restrict__ Kmat,
                                                const float* __restrict__ rvec,
                                                float* __restrict__ cvec) {
  const int bid = blockIdx.x;
  const int h  = bid >> 5;
  const int cc = (bid >> 3) & 3;
  const int rc = bid & 7;
  __shared__ float ainv[128];
  const int t = threadIdx.x;
  if (t < 128) ainv[t] = MUV * frcp(rvec[h * SEQ + rc * 128 + t]);
  __syncthreads();
  const int j = cc * 256 + t;
  const float* Kp = Kmat + ((size_t)h * SEQ + rc * 128) * SEQ + j;
  float cj = 0.f;
#pragma unroll 8
  for (int i = 0; i < 128; i++) cj += Kp[(size_t)i * SEQ] * ainv[i];
  atomicAdd(&cvec[h * SEQ + j], cj);
}

// Final: p_ij = Kmat_ij * (1/r_i) * (nu/c_j)  (== 1024*pi), written in-place over Kmat,
// and out[i][d] = sum_j p_ij V[j][d]. 64-row block, 256 threads, 4x4 micro-tile.
__global__ __launch_bounds__(256) void final_kernel(float* __restrict__ Pmat,
                                                    const float* __restrict__ rvec,
                                                    const float* __restrict__ cvec,
                                                    const float* __restrict__ V,
                                                    float* __restrict__ out) {
  __shared__ __align__(16) float Pt[64][DIM + 4];
  __shared__ __align__(16) float Vt[64][DIM + 4];
  __shared__ float arow[64];
  const int h  = blockIdx.y;
  const int r0 = blockIdx.x * 64;
  const int t  = threadIdx.x;
  const int ty = t >> 4;
  const int tx = t & 15;
  const float* Vh = V + (size_t)h * SEQ * DIM;

  if (t < 64) arow[t] = frcp(rvec[h * SEQ + r0 + t]);  // 1024*mu*rcp(r) == rcp(r)
  __syncthreads();

  float o[4][4] = {};

  for (int jc = 0; jc < 16; jc++) {
    const int j0 = jc * 64;
    // stage V tile
#pragma unroll
    for (int ro = 0; ro < 4; ro++) {
      const int r = ro * 16 + ty;
      *(float4*)&Vt[r][tx * 4] = *(const float4*)(Vh + (size_t)(j0 + r) * DIM + tx * 4);
    }
    // b for this thread's 4 columns
    const float4 cv = *(const float4*)(cvec + h * SEQ + j0 + tx * 4);
    float4 b4;
    b4.x = MUV * frcp(cv.x); b4.y = MUV * frcp(cv.y);
    b4.z = MUV * frcp(cv.z); b4.w = MUV * frcp(cv.w);
    // load Kexp tile, finalize p, write back in place, stage to LDS
#pragma unroll
    for (int ro = 0; ro < 4; ro++) {
      const int r = ro * 16 + ty;
      float* gp = Pmat + ((size_t)h * SEQ + r0 + r) * SEQ + j0 + tx * 4;
      const float4 k4 = *(const float4*)gp;
      const float ar = arow[r];
      float4 p4;
      p4.x = ar * b4.x * k4.x; p4.y = ar * b4.y * k4.y;
      p4.z = ar * b4.z * k4.z; p4.w = ar * b4.w * k4.w;
      *(float4*)gp = p4;
      *(float4*)&Pt[r][tx * 4] = p4;
    }
    __syncthreads();
    // o += P * V   (rows ty+16i, d-cols tx*4..+3)
#pragma unroll 2
    for (int c0 = 0; c0 < 64; c0 += 4) {
      float4 pa[4], vv[4];
#pragma unroll
      for (int i = 0; i < 4; i++) pa[i] = *(const float4*)&Pt[ty + 16 * i][c0];
#pragma unroll
      for (int k = 0; k < 4; k++) vv[k] = *(const float4*)&Vt[c0 + k][tx * 4];
#pragma unroll
      for (int i = 0; i < 4; i++) {
        o[i][0] += pa[i].x * vv[0].x + pa[i].y * vv[1].x + pa[i].z * vv[2].x + pa[i].w * vv[3].x;
        o[i][1] += pa[i].x * vv[0].y + pa[i].y * vv[1].y + pa[i].z * vv[2].y + pa[i].w * vv[3].y;
        o[i][2] += pa[i].x * vv[0].z + pa[i].y * vv[1].z + pa[i].z * vv[2].z + pa[i].w * vv[3].z;
        o[i][3] += pa[i].x * vv[0].w + pa[i].y * vv[1].w + pa[i].z * vv[2].w + pa[i].w * vv[3].w;
      }
    }
    __syncthreads();
  }
#pragma unroll
  for (int i = 0; i < 4; i++) {
    *(float4*)(out + ((size_t)h * SEQ + r0 + ty + 16 * i) * DIM + tx * 4) =
        make_float4(o[i][0], o[i][1], o[i][2], o[i][3]);
  }
}

extern "C" void kernel_launch(void* const* d_in, const int* in_sizes, int n_in,
                              void* d_out, int out_size, void* d_ws, size_t ws_size,
                              hipStream_t stream) {
  const float* Q   = (const float*)d_in[0];
  const float* Kin = (const float*)d_in[1];
  const float* V   = (const float*)d_in[2];
  float* out  = (float*)d_out;
  float* Pmat = out + (size_t)NH * SEQ * DIM;   // p_attn region doubles as Kexp scratch
  float* rvec = (float*)d_ws;                   // NH*SEQ floats
  float* cvec = rvec + NH * SEQ;                // NH*SEQ floats

  qk_kernel<<<dim3(8, 8, NH), 256, 0, stream>>>(Q, Kin, Pmat);
  for (int it = 0; it < 10; it++) {
    row_pass<<<NH * SEQ / 4, 256, 0, stream>>>(Pmat, cvec, rvec, it == 0 ? 1 : 0);
    hipMemsetAsync(cvec, 0, NH * SEQ * sizeof(float), stream);
    col_pass<<<512, 256, 0, stream>>>(Pmat, rvec, cvec);
  }
  final_kernel<<<dim3(16, NH), 256, 0, stream>>>(Pmat, rvec, cvec, V, out);
}